// Round 14
// baseline (270.349 us; speedup 1.0000x reference)
//
#include <hip/hip_runtime.h>

#define L_DIM 2048
#define C_DIM 512
#define B_DIM 8

typedef __attribute__((ext_vector_type(8))) short bf16x8;   // 8 bf16 = 4 VGPR
typedef __attribute__((ext_vector_type(4))) float f32x4;    // MFMA acc

constexpr size_t SQ  = (size_t)L_DIM * C_DIM;   // per-batch q/k/v stride
constexpr size_t SAT = (size_t)L_DIM * L_DIM;   // per-batch attn stride
constexpr size_t MC  = (size_t)B_DIM * L_DIM * C_DIM;
constexpr int BL = B_DIM * L_DIM;               // 16384

// softmax scratch (device globals -- no ws footprint, rewritten every launch)
__device__ float g_psr[16][BL];   // row partial expsum [ktile][b*L+row]
__device__ float g_psc[16][BL];   // col partial expsum [qtile][b*L+col]

__device__ __forceinline__ float bf2f(ushort u) {
  union { float f; unsigned int i; } c; c.i = ((unsigned int)u) << 16; return c.f;
}
__device__ __forceinline__ ushort f2bf(float f) {
  union { float f; unsigned int i; } c; c.f = f;
  unsigned int lsb = (c.i >> 16) & 1u;
  return (ushort)((c.i + 0x7FFFu + lsb) >> 16);
}

__device__ __forceinline__ float wave_red_sum(float v) {
  #pragma unroll
  for (int o = 1; o < 64; o <<= 1) v += __shfl_xor(v, o, 64);
  return v;
}

// async global->LDS, 16B per lane (dest = wave-uniform base + lane*16)
__device__ __forceinline__ void glds16(const ushort* g, ushort* l) {
  __builtin_amdgcn_global_load_lds(
      (const __attribute__((address_space(1))) void*)g,
      (__attribute__((address_space(3))) void*)l, 16, 0, 0);
}

// BK=32 LDS slot functions (4 x 16B chunks per 64 B row). 16 consecutive rows
// cover all 8 bank-quads exactly twice (2-way = free). Bijective in c per row.
__device__ __forceinline__ int slot32(int r, int c) {          // c = chunk 0..3
  return (((c ^ (r & 3)) + (r >> 2)) & 3);
}
__device__ __forceinline__ int ch32(int r, int sl) {           // inverse
  return (((sl - (r >> 2)) & 3) ^ (r & 3));
}
__device__ __forceinline__ int slotC(int r, int q4) {          // q4 = c>>3, 0..15
  return ((q4 ^ (r & 15)) + (r >> 4)) & 15;
}

// XCD-chunked swizzle (T1). nwg % 8 == 0.
__device__ __forceinline__ int xcd_swz(int bid, int nwg) {
  return (bid & 7) * (nwg >> 3) + (bid >> 3);
}

// ---------------------------------------------------------------------------
// 128x128 bf16 MFMA GEMM core, D = A.B^T. BK=32, 256 thr = 4 waves (2x2).
// 3-buffer LDS pipeline (48 KiB -> 3 blocks/CU), 2-tile lookahead, counted
// vmcnt (T4, schedule correctness-proven in R11; occupancy fixed here):
//   prologue: stage(t0); stage(t1); vmcnt(4)+lgkmcnt(0); barrier
//   iter kt:  stage(kt+2) [4 glds]; ds_read frags; 16 MFMA; vmcnt(4)
//             [kt+1 landed by FIFO, kt+2's 4 stay in flight]; s_barrier.
// sched_barrier(0) pins issue order around the counted waits.
// STATS (qkt): epilogue stores exp(val); row/col partial sums -> dev globals.
// SCALE (pv):  prologue folds sm_combine (16 partials -> 1/s); epilogue *=.
// EPI: 0 row-major store (obN,ldo), 1 transposed (obT,ldoT), 2 both.
// ---------------------------------------------------------------------------
template <bool STATS, bool SCALE>
__device__ __forceinline__ void gemm_core128(
    const ushort* __restrict__ Ab, const ushort* __restrict__ Bb,
    const float* __restrict__ bias,
    ushort* __restrict__ obN, ushort* __restrict__ obT,
    const int K, const int lda, const int ldb, const int ldo, const int ldoT,
    const int m0, const int n0, const float scale, const int EPI,
    const int sb, const float* __restrict__ ps)   // ps: pre-offset partials (16 x BL)
{
  __shared__ __align__(16) ushort lds[24576];   // 48 KiB: 3 x (A 4096 | B 4096 ushorts)
  __shared__ float sinv[128];

  const int t = threadIdx.x;
  const int lane = t & 63, w = t >> 6;
  const int wr = w >> 1, wc = w & 1;
  const int l16 = lane & 15, lhi = lane >> 4;   // lhi = chunk 0..3 (k = lhi*8)
  const int lrow4 = lane >> 2, lsl4 = lane & 3;

  // fused sm_combine: 1/sum for this block's 128 rows (read only in epilogue,
  // after many barriers; prologue lgkmcnt(0)+barrier publishes the ds_write).
  if (SCALE) {
    if (t < 128) {
      float s = 0.f;
      #pragma unroll
      for (int p = 0; p < 16; ++p) s += ps[(size_t)p * BL + t];
      sinv[t] = 1.0f / s;
    }
  }

  f32x4 acc[4][4];
  #pragma unroll
  for (int i = 0; i < 4; ++i)
    #pragma unroll
    for (int j = 0; j < 4; ++j) { f32x4 zv = {0.f, 0.f, 0.f, 0.f}; acc[i][j] = zv; }

  auto stage = [&](ushort* base, int k0) {       // 4 glds16 per thread
    #pragma unroll
    for (int p = 0; p < 2; ++p) {
      const int rbase = w * 32 + p * 16;         // 16 rows per call
      const int rr = rbase + lrow4;
      const int ch = ch32(rr, lsl4);             // inverse-swizzled global src
      glds16(Ab + (size_t)(m0 + rr) * lda + k0 + ch * 8, base + rbase * 32);
    }
    #pragma unroll
    for (int p = 0; p < 2; ++p) {
      const int rbase = w * 32 + p * 16;
      const int rr = rbase + lrow4;
      const int ch = ch32(rr, lsl4);
      glds16(Bb + (size_t)(n0 + rr) * ldb + k0 + ch * 8, base + 4096 + rbase * 32);
    }
  };

  const int KT = K >> 5;                         // BK = 32
  ushort* cur = lds;
  ushort* nxt = lds + 8192;
  ushort* fut = lds + 16384;
  stage(cur, 0);
  stage(nxt, 32);
  __builtin_amdgcn_sched_barrier(0);
  asm volatile("s_waitcnt vmcnt(4) lgkmcnt(0)" ::: "memory");  // t0 in; sinv committed
  __builtin_amdgcn_s_barrier();
  __builtin_amdgcn_sched_barrier(0);

  for (int kt = 0; kt < KT; ++kt) {
    if (kt + 2 < KT) stage(fut, (kt + 2) << 5);  // flies across the barrier below
    const ushort* As = cur;
    const ushort* Bs = cur + 4096;
    bf16x8 af[4], bg[4];
    #pragma unroll
    for (int i = 0; i < 4; ++i) {
      const int ra = wr * 64 + i * 16 + l16;
      af[i] = *(const bf16x8*)&As[ra * 32 + 8 * slot32(ra, lhi)];
      const int rb = wc * 64 + i * 16 + l16;
      bg[i] = *(const bf16x8*)&Bs[rb * 32 + 8 * slot32(rb, lhi)];
    }
    #pragma unroll
    for (int i = 0; i < 4; ++i)
      #pragma unroll
      for (int j = 0; j < 4; ++j)
        acc[i][j] = __builtin_amdgcn_mfma_f32_16x16x32_bf16(af[i], bg[j], acc[i][j], 0, 0, 0);
    __builtin_amdgcn_sched_barrier(0);
    if (kt + 2 < KT)      asm volatile("s_waitcnt vmcnt(4)" ::: "memory");  // kt+1 landed
    else if (kt + 1 < KT) asm volatile("s_waitcnt vmcnt(0)" ::: "memory");  // last tile in
    __builtin_amdgcn_s_barrier();               // all waves done reading cur
    __builtin_amdgcn_sched_barrier(0);
    ushort* tmp = cur; cur = nxt; nxt = fut; fut = tmp;
  }

  // ---- epilogue: bounce C tile (128x128 bf16) through swizzled LDS ----
  // (final loop barrier sealed all LDS reads; Cs spans buffers 0-1)
  ushort* Cs = lds;                        // 32 KiB
  #pragma unroll
  for (int i = 0; i < 4; ++i) {
    #pragma unroll
    for (int j = 0; j < 4; ++j) {
      const int er = wr * 64 + i * 16 + lhi * 4;       // C/D: row=(lane>>4)*4+reg
      const int ec = wc * 64 + j * 16 + l16;           //      col=lane&15
      const float bv = bias ? bias[n0 + ec] : 0.f;
      #pragma unroll
      for (int r = 0; r < 4; ++r) {
        const int rr = er + r;
        float val = acc[i][j][r] * scale + bv;
        if (STATS) val = __expf(val);      // store P_unnorm = exp(score)
        if (SCALE) val *= sinv[rr];
        Cs[rr * 128 + 8 * slotC(rr, ec >> 3) + (ec & 7)] = f2bf(val);
      }
    }
  }
  __syncthreads();
  if (EPI == 0 || EPI == 2) {
    #pragma unroll
    for (int p = 0; p < 8; ++p) {
      const int id = p * 256 + t, r = id >> 4, cc = id & 15;
      const bf16x8 v = *(const bf16x8*)&Cs[r * 128 + 8 * slotC(r, cc)];
      *(bf16x8*)(obN + (size_t)(m0 + r) * ldo + n0 + cc * 8) = v;
    }
  }
  if (EPI >= 1) {
    #pragma unroll
    for (int p = 0; p < 8; ++p) {
      const int id = p * 256 + t, c = id >> 4, rs = id & 15;
      bf16x8 tv;
      #pragma unroll
      for (int jj = 0; jj < 8; ++jj) {
        const int r2 = rs * 8 + jj;
        tv[jj] = (short)Cs[r2 * 128 + 8 * slotC(r2, c >> 3) + (c & 7)];
      }
      *(bf16x8*)(obT + (size_t)(n0 + c) * ldoT + m0 + rs * 8) = tv;
    }
  }

  if (STATS) {
    // partial sums of the stored bf16 P values (exactly what pv re-reads).
    if (t < 128) {                          // row orientation (attn rows)
      const int r = t;
      float s = 0.f;
      #pragma unroll
      for (int cc = 0; cc < 16; ++cc) {
        const bf16x8 v8 = *(const bf16x8*)&Cs[r * 128 + 8 * slotC(r, cc)];
        #pragma unroll
        for (int j = 0; j < 8; ++j) s += bf2f((ushort)v8[j]);
      }
      g_psr[n0 >> 7][sb * L_DIM + m0 + r] = s;
    } else {                                // col orientation (attnT rows)
      const int c = t - 128;
      float s = 0.f;
      #pragma unroll 8
      for (int r2 = 0; r2 < 128; ++r2)
        s += bf2f(Cs[r2 * 128 + 8 * slotC(r2, c >> 3) + (c & 7)]);
      g_psc[m0 >> 7][sb * L_DIM + n0 + c] = s;
    }
  }
}

// ---- wrappers (1D grids + XCD swizzle) -------------------------------------
// all 4 projections: lid = x(16) | y(4) | b(8) | pj(4)
__global__ __launch_bounds__(256, 3) void gemm_proj(
    const ushort* __restrict__ x1T, const ushort* __restrict__ x2T,
    const ushort* __restrict__ wbf,
    const float* __restrict__ b_q, const float* __restrict__ b_k,
    const float* __restrict__ b_v1, const float* __restrict__ b_v2,
    ushort* __restrict__ q, ushort* __restrict__ kb,
    ushort* __restrict__ v1T, ushort* __restrict__ v2T)
{
  const int lid = xcd_swz(blockIdx.x, 2048);
  const int x = lid & 15, y = (lid >> 4) & 3, rest = lid >> 6;
  const int b = rest & 7, pj = rest >> 3;
  const ushort* A = ((pj & 1) ? x2T : x1T) + (size_t)b * SQ;
  const ushort* B = wbf + (size_t)pj * (C_DIM * C_DIM);
  const float* bias = pj == 0 ? b_q : pj == 1 ? b_k : pj == 2 ? b_v1 : b_v2;
  if (pj < 2) {
    ushort* oN = (pj == 0 ? q : kb) + (size_t)b * SQ;
    gemm_core128<false, false>(A, B, bias, oN, nullptr, C_DIM, C_DIM, C_DIM,
                               C_DIM, 0, x * 128, y * 128, 1.0f, 0, 0, nullptr);
  } else {
    ushort* oT = (pj == 2 ? v1T : v2T) + (size_t)b * SQ;
    gemm_core128<false, false>(A, B, bias, nullptr, oT, C_DIM, C_DIM, C_DIM,
                               0, L_DIM, x * 128, y * 128, 1.0f, 1, 0, nullptr);
  }
}

// P_unnorm = exp(q.k^T * scale) -> attn, attnT, partial sums.
// lid = x(16) | y(16) | b(8)
__global__ __launch_bounds__(256, 3) void gemm_qkt(
    const ushort* __restrict__ qb, const ushort* __restrict__ kb,
    ushort* __restrict__ attn, ushort* __restrict__ attnT, const float scale)
{
  const int lid = xcd_swz(blockIdx.x, 2048);
  const int x = lid & 15, y = (lid >> 4) & 15, b = lid >> 8;
  gemm_core128<true, false>(qb + (size_t)b * SQ, kb + (size_t)b * SQ, nullptr,
               attn + (size_t)b * SAT, attnT + (size_t)b * SAT,
               C_DIM, C_DIM, C_DIM, L_DIM, L_DIM,
               x * 128, y * 128, scale, 2, b, nullptr);
}

// both PVs (sm_combine fused in prologue): lid = x(16) | y(4) | which(2) | b(8)
__global__ __launch_bounds__(256, 3) void gemm_pv(
    const ushort* __restrict__ attn, const ushort* __restrict__ attnT,
    const ushort* __restrict__ v1T, const ushort* __restrict__ v2T,
    ushort* __restrict__ vk, ushort* __restrict__ vq)
{
  const int lid = xcd_swz(blockIdx.x, 1024);
  const int x = lid & 15, y = (lid >> 4) & 3, rest = lid >> 6;
  const int which = rest & 1, b = rest >> 1;
  const ushort* A = (which ? attnT : attn) + (size_t)b * SAT;
  const ushort* B = (which ? v1T : v2T) + (size_t)b * SQ;
  ushort* o = (which ? vq : vk) + (size_t)b * SQ;
  const int m0 = x * 128;
  const float* ps = (which ? &g_psc[0][0] : &g_psr[0][0]) + b * L_DIM + m0;
  gemm_core128<false, true>(A, B, nullptr, o, nullptr,
               L_DIM, L_DIM, L_DIM, C_DIM, 0,
               m0, y * 128, 1.0f, 0, b, ps);
}

// ---------------------------------------------------------------------------
// x [B][C][L] fp32 -> xT [B][L][C] bf16, both inputs in one dispatch.
// ---------------------------------------------------------------------------
__global__ __launch_bounds__(256) void xpose(const float* __restrict__ x1,
                                             const float* __restrict__ x2,
                                             ushort* __restrict__ xT)
{
  __shared__ float s[64][65];
  const int z = blockIdx.z, l0 = blockIdx.x * 64, c0 = blockIdx.y * 64;
  const int t = threadIdx.x;
  const float* xb = (z < 8 ? x1 : x2) + ((size_t)(z & 7) * C_DIM + c0) * L_DIM + l0;
  #pragma unroll
  for (int p = 0; p < 16; ++p) {
    const int c = p * 4 + (t >> 6);
    s[c][t & 63] = xb[(size_t)c * L_DIM + (t & 63)];
  }
  __syncthreads();
  ushort* ob = xT + (size_t)z * SQ + (size_t)l0 * C_DIM + c0;
  #pragma unroll
  for (int p = 0; p < 16; ++p) {
    const int l = p * 4 + (t >> 6);
    ob[(size_t)l * C_DIM + (t & 63)] = f2bf(s[t & 63][l]);
  }
}

// all 4 weights fp32 -> bf16 in one dispatch
__global__ __launch_bounds__(256) void cvtw4(const float* __restrict__ a,
    const float* __restrict__ b, const float* __restrict__ c,
    const float* __restrict__ d, ushort* __restrict__ o)
{
  const int i = blockIdx.x * 256 + threadIdx.x;
  const int sel = i >> 18;
  const float* w = sel == 0 ? a : sel == 1 ? b : sel == 2 ? c : d;
  o[i] = f2bf(w[i & 262143]);
}

// ---------------------------------------------------------------------------
// LayerNorm over C + cross skip + transpose back to (B, C, L).
// v2: 32 l-rows per block, bf16 LDS tile (33 KB) -> 128 B out-write segments.
// ---------------------------------------------------------------------------
__global__ __launch_bounds__(256) void ln_out(const ushort* __restrict__ vk,
    const ushort* __restrict__ vq, const float* __restrict__ x1,
    const float* __restrict__ x2, const float* __restrict__ gamma,
    const float* __restrict__ beta, float* __restrict__ out)
{
  __shared__ __align__(16) ushort s[32][520];   // bf16 (v + x), padded pitch
  __shared__ float mu[32], rsd[32];
  __shared__ float gb[512], bb[512];
  const int t = threadIdx.x;
  const int b = blockIdx.y, l0 = blockIdx.x * 32, which = blockIdx.z;
  const ushort* vx = which ? vq : vk;
  const float* xo = which ? x2 : x1;
  float* obase = out + (size_t)which * MC;
  #pragma unroll
  for (int r = 0; r < 2; ++r) { gb[r * 256 + t] = gamma[r * 256 + t]; bb[r * 256 + t] = beta[r * 256 + t]; }
  // 1) load v tile (bf16 passthrough, coalesced in c)
  const ushort* vb = vx + ((size_t)b * L_DIM + l0) * C_DIM;
  #pragma unroll
  for (int p = 0; p < 8; ++p) {
    const int id = p * 256 + t;             // 2048 chunks of 8 bf16
    const int l = id >> 6, cb = (id & 63) * 8;
    *(bf16x8*)&s[l][cb] = *(const bf16x8*)&vb[(size_t)l * C_DIM + cb];
  }
  __syncthreads();
  // 2) add skip (x read coalesced in l: 128 B segments)
  const float* xb = xo + (size_t)b * C_DIM * L_DIM + l0;
  for (int it = 0; it < 64; ++it) {
    const int idx = it * 256 + t, c = idx >> 5, l = idx & 31;
    s[l][c] = f2bf(bf2f(s[l][c]) + xb[(size_t)c * L_DIM + l]);
  }
  __syncthreads();
  // 3) stats: wave w handles rows w*8 .. w*8+7; lane covers 8 c's
  const int w = t >> 6, lane = t & 63;
  #pragma unroll
  for (int rr = 0; rr < 8; ++rr) {
    const int l = w * 8 + rr;
    const bf16x8 v8 = *(const bf16x8*)&s[l][lane * 8];
    float sum = 0.f, sq = 0.f;
    #pragma unroll
    for (int j = 0; j < 8; ++j) {
      const float v = bf2f((ushort)v8[j]);
      sum += v; sq = fmaf(v, v, sq);
    }
    sum = wave_red_sum(sum); sq = wave_red_sum(sq);
    if (lane == 0) {
      const float m = sum * (1.f / 512.f);
      const float var = sq * (1.f / 512.f) - m * m;
      mu[l] = m; rsd[l] = rsqrtf(var + 1e-5f);
    }
  }
  __syncthreads();
  // 4) normalize + write (coalesced in l: 128 B segments)
  float* ob = obase + (size_t)b * C_DIM * L_DIM + l0;
  for (int it = 0; it < 64; ++it) {
    const int idx = it * 256 + t, c = idx >> 5, l = idx & 31;
    const float v = (bf2f(s[l][c]) - mu[l]) * rsd[l] * gb[c] + bb[c];
    ob[(size_t)c * L_DIM + l] = v;
  }
}

// ---------------------------------------------------------------------------
extern "C" void kernel_launch(void* const* d_in, const int* in_sizes, int n_in,
                              void* d_out, int out_size, void* d_ws, size_t ws_size,
                              hipStream_t stream) {
  const float* x1   = (const float*)d_in[0];
  const float* x2   = (const float*)d_in[1];
  const float* w_q  = (const float*)d_in[2];
  const float* b_q  = (const float*)d_in[3];
  const float* w_k  = (const float*)d_in[4];
  const float* b_k  = (const float*)d_in[5];
  const float* w_v1 = (const float*)d_in[6];
  const float* b_v1 = (const float*)d_in[7];
  const float* w_v2 = (const float*)d_in[8];
  const float* b_v2 = (const float*)d_in[9];
  const float* gamma= (const float*)d_in[10];
  const float* beta = (const float*)d_in[11];
  float* out = (float*)d_out;

  // ---- ws: exactly 128 MiB bf16 ----
  ushort* q    = (ushort*)d_ws;        // 16 MiB
  ushort* kbuf = q + MC;               // 16 MiB
  ushort* v1T  = kbuf + MC;            // 16 MiB  [C][L] per batch
  ushort* v2T  = v1T + MC;             // 16 MiB
  ushort* attn = v2T + MC;             // 64 MiB  [q][k] per batch (P_unnorm)
  // overlays in the not-yet-written attn region (dead before QK^T):
  ushort* x1T = attn;                  // 16 MiB  [B][L][C]  (x2T = x1T + MC)
  ushort* wbf = attn + 2 * MC;         // 4 x 256K = 2 MiB (q|k|v1|v2)
  // PV outputs in regions dead after QK^T:
  ushort* vkbuf = kbuf;
  ushort* vqbuf = q;
  // attnT [k][q] bf16 fills d_out (64 MiB), dead before ln writes:
  ushort* attnT = (ushort*)d_out;

  const float iscale = 0.044194173824159216f;  // 1/sqrt(512)
  const dim3 blk256(256);

  // 1) weights fp32 -> bf16
  cvtw4<<<4096, blk256, 0, stream>>>(w_q, w_k, w_v1, w_v2, wbf);
  // 2) x1,x2 -> xT bf16
  xpose<<<dim3(32, 8, 16), blk256, 0, stream>>>(x1, x2, x1T);
  // 3) all 4 projections
  gemm_proj<<<2048, blk256, 0, stream>>>(x1T, x1T + MC, wbf,
      b_q, b_k, b_v1, b_v2, q, kbuf, v1T, v2T);
  // 4) P_unnorm = exp(q.k^T * iscale) -> attn, attnT + partial sums
  gemm_qkt<<<2048, blk256, 0, stream>>>(q, kbuf, attn, attnT, iscale);
  // 5) both PVs (sm_combine fused into pv prologue)
  gemm_pv<<<1024, blk256, 0, stream>>>(attn, attnT, v1T, v2T, vkbuf, vqbuf);
  // 6) LN + skip + transpose back (clobbers attnT -- now dead)
  ln_out<<<dim3(L_DIM / 32, B_DIM, 2), blk256, 0, stream>>>(
      vkbuf, vqbuf, x1, x2, gamma, beta, out);
}

// Round 15
// 239.630 us; speedup vs baseline: 1.1282x; 1.1282x over previous
//
#include <hip/hip_runtime.h>

#define L_DIM 2048
#define C_DIM 512
#define B_DIM 8

typedef __attribute__((ext_vector_type(8))) short bf16x8;   // 8 bf16 = 4 VGPR
typedef __attribute__((ext_vector_type(4))) float f32x4;    // MFMA acc

constexpr size_t SQ  = (size_t)L_DIM * C_DIM;   // per-batch q/k/v stride
constexpr size_t SAT = (size_t)L_DIM * L_DIM;   // per-batch attn stride
constexpr size_t MC  = (size_t)B_DIM * L_DIM * C_DIM;
constexpr int BL = B_DIM * L_DIM;               // 16384

// softmax scratch (device globals -- no ws footprint, rewritten every launch)
__device__ float g_psr[16][BL];   // row partial expsum [ktile][b*L+row]
__device__ float g_psc[16][BL];   // col partial expsum [qtile][b*L+col]

__device__ __forceinline__ float bf2f(ushort u) {
  union { float f; unsigned int i; } c; c.i = ((unsigned int)u) << 16; return c.f;
}
__device__ __forceinline__ ushort f2bf(float f) {
  union { float f; unsigned int i; } c; c.f = f;
  unsigned int lsb = (c.i >> 16) & 1u;
  return (ushort)((c.i + 0x7FFFu + lsb) >> 16);
}

__device__ __forceinline__ float wave_red_sum(float v) {
  #pragma unroll
  for (int o = 1; o < 64; o <<= 1) v += __shfl_xor(v, o, 64);
  return v;
}

// async global->LDS, 16B per lane (dest = wave-uniform base + lane*16)
__device__ __forceinline__ void glds16(const ushort* g, ushort* l) {
  __builtin_amdgcn_global_load_lds(
      (const __attribute__((address_space(1))) void*)g,
      (__attribute__((address_space(3))) void*)l, 16, 0, 0);
}

// LDS slot functions: row-group rotation spreads 16 consecutive rows over all
// 8 bank-quads (2-way aliasing = free). Bijective in c for fixed r.
__device__ __forceinline__ int slotAB(int r, int c) {          // c = 16B chunk 0..7
  return (((c ^ (r & 7)) + (r >> 3)) & 7);
}
__device__ __forceinline__ int chAB(int r, int sl) {           // inverse
  return ((sl - (r >> 3)) & 7) ^ (r & 7);
}
__device__ __forceinline__ int slotC(int r, int q4) {          // q4 = c>>3, 0..15
  return ((q4 ^ (r & 15)) + (r >> 4)) & 15;
}

// XCD-chunked swizzle (T1). nwg % 8 == 0.
__device__ __forceinline__ int xcd_swz(int bid, int nwg) {
  return (bid & 7) * (nwg >> 3) + (bid >> 3);
}

// ---------------------------------------------------------------------------
// 128x128 bf16 MFMA GEMM core, D = A.B^T. BK=64, 256 thr = 4 waves (2x2),
// single-buffered 32 KiB LDS (m97 structure), glds staging both operands.
// STATS (qkt): epilogue stores exp(val); per-tile row/col partial sums of the
//              stored bf16 -> device globals (max-free softmax, scores~N(0,1)).
// SCALE (pv):  prologue folds sm_combine (sum 16 partials -> 1/s into LDS);
//              epilogue multiplies by sinv[row].
// EPI: 0 row-major store (obN,ldo), 1 transposed (obT,ldoT), 2 both.
// ---------------------------------------------------------------------------
template <bool STATS, bool SCALE>
__device__ __forceinline__ void gemm_core128(
    const ushort* __restrict__ Ab, const ushort* __restrict__ Bb,
    const float* __restrict__ bias,
    ushort* __restrict__ obN, ushort* __restrict__ obT,
    const int K, const int lda, const int ldb, const int ldo, const int ldoT,
    const int m0, const int n0, const float scale, const int EPI,
    const int sb, const float* __restrict__ ps)   // ps: pre-offset partials (16 x BL)
{
  __shared__ __align__(16) ushort lds[16384];   // 32 KiB: A 8K | B 8K ushorts
  __shared__ float sinv[128];

  const int t = threadIdx.x;
  const int lane = t & 63, w = t >> 6;
  const int wr = w >> 1, wc = w & 1;
  const int l16 = lane & 15, lhi = lane >> 4;
  const int lrow = lane >> 3, lsl = lane & 7;

  ushort* As = lds;
  ushort* Bs = lds + 8192;

  // fused sm_combine: 1/sum for this block's 128 rows (sinv read only in the
  // epilogue, after multiple barriers -> ordering safe).
  if (SCALE) {
    if (t < 128) {
      float s = 0.f;
      #pragma unroll
      for (int p = 0; p < 16; ++p) s += ps[(size_t)p * BL + t];
      sinv[t] = 1.0f / s;
    }
  }

  f32x4 acc[4][4];
  #pragma unroll
  for (int i = 0; i < 4; ++i)
    #pragma unroll
    for (int j = 0; j < 4; ++j) { f32x4 zv = {0.f, 0.f, 0.f, 0.f}; acc[i][j] = zv; }

  const int KT = K >> 6;
  for (int kt = 0; kt < KT; ++kt) {
    const int k0 = kt << 6;
    __syncthreads();                       // prev compute done with LDS
    #pragma unroll
    for (int p = 0; p < 4; ++p) {
      const int rbase = w * 32 + p * 8;
      const int rr = rbase + lrow;
      const int ch = chAB(rr, lsl);        // inverse-swizzled global source
      glds16(Ab + (size_t)(m0 + rr) * lda + k0 + ch * 8, As + rbase * 64);
      glds16(Bb + (size_t)(n0 + rr) * ldb + k0 + ch * 8, Bs + rbase * 64);
    }
    __syncthreads();                       // drains vmcnt -> LDS ready
    #pragma unroll
    for (int ks = 0; ks < 2; ++ks) {
      bf16x8 af[4], bg[4];
      #pragma unroll
      for (int i = 0; i < 4; ++i) {
        const int ra = wr * 64 + i * 16 + l16;
        af[i] = *(const bf16x8*)&As[ra * 64 + 8 * slotAB(ra, ks * 4 + lhi)];
        const int rb = wc * 64 + i * 16 + l16;
        bg[i] = *(const bf16x8*)&Bs[rb * 64 + 8 * slotAB(rb, ks * 4 + lhi)];
      }
      #pragma unroll
      for (int i = 0; i < 4; ++i)
        #pragma unroll
        for (int j = 0; j < 4; ++j)
          acc[i][j] = __builtin_amdgcn_mfma_f32_16x16x32_bf16(af[i], bg[j], acc[i][j], 0, 0, 0);
    }
  }

  // ---- epilogue: bounce C tile (128x128 bf16) through swizzled LDS ----
  __syncthreads();
  ushort* Cs = lds;                        // 32 KiB
  #pragma unroll
  for (int i = 0; i < 4; ++i) {
    #pragma unroll
    for (int j = 0; j < 4; ++j) {
      const int er = wr * 64 + i * 16 + lhi * 4;       // C/D: row=(lane>>4)*4+reg
      const int ec = wc * 64 + j * 16 + l16;           //      col=lane&15
      const float bv = bias ? bias[n0 + ec] : 0.f;
      #pragma unroll
      for (int r = 0; r < 4; ++r) {
        const int rr = er + r;
        float val = acc[i][j][r] * scale + bv;
        if (STATS) val = __expf(val);      // store P_unnorm = exp(score)
        if (SCALE) val *= sinv[rr];
        Cs[rr * 128 + 8 * slotC(rr, ec >> 3) + (ec & 7)] = f2bf(val);
      }
    }
  }
  __syncthreads();
  if (EPI == 0 || EPI == 2) {
    #pragma unroll
    for (int p = 0; p < 8; ++p) {
      const int id = p * 256 + t, r = id >> 4, cc = id & 15;
      const bf16x8 v = *(const bf16x8*)&Cs[r * 128 + 8 * slotC(r, cc)];
      *(bf16x8*)(obN + (size_t)(m0 + r) * ldo + n0 + cc * 8) = v;
    }
  }
  if (EPI >= 1) {
    #pragma unroll
    for (int p = 0; p < 8; ++p) {
      const int id = p * 256 + t, c = id >> 4, rs = id & 15;
      bf16x8 tv;
      #pragma unroll
      for (int jj = 0; jj < 8; ++jj) {
        const int r2 = rs * 8 + jj;
        tv[jj] = (short)Cs[r2 * 128 + 8 * slotC(r2, c >> 3) + (c & 7)];
      }
      *(bf16x8*)(obT + (size_t)(n0 + c) * ldoT + m0 + rs * 8) = tv;
    }
  }

  if (STATS) {
    // partial sums of the stored bf16 P values (exactly what pv re-reads).
    if (t < 128) {                          // row orientation (attn rows)
      const int r = t;
      float s = 0.f;
      #pragma unroll
      for (int cc = 0; cc < 16; ++cc) {
        const bf16x8 v8 = *(const bf16x8*)&Cs[r * 128 + 8 * slotC(r, cc)];
        #pragma unroll
        for (int j = 0; j < 8; ++j) s += bf2f((ushort)v8[j]);
      }
      g_psr[n0 >> 7][sb * L_DIM + m0 + r] = s;
    } else {                                // col orientation (attnT rows)
      const int c = t - 128;
      float s = 0.f;
      #pragma unroll 8
      for (int r2 = 0; r2 < 128; ++r2)
        s += bf2f(Cs[r2 * 128 + 8 * slotC(r2, c >> 3) + (c & 7)]);
      g_psc[m0 >> 7][sb * L_DIM + n0 + c] = s;
    }
  }
}

// ---- wrappers (1D grids + XCD swizzle) -------------------------------------
// all 4 projections: lid = x(16) | y(4) | b(8) | pj(4)
__global__ __launch_bounds__(256, 4) void gemm_proj(
    const ushort* __restrict__ x1T, const ushort* __restrict__ x2T,
    const ushort* __restrict__ wbf,
    const float* __restrict__ b_q, const float* __restrict__ b_k,
    const float* __restrict__ b_v1, const float* __restrict__ b_v2,
    ushort* __restrict__ q, ushort* __restrict__ kb,
    ushort* __restrict__ v1T, ushort* __restrict__ v2T)
{
  const int lid = xcd_swz(blockIdx.x, 2048);
  const int x = lid & 15, y = (lid >> 4) & 3, rest = lid >> 6;
  const int b = rest & 7, pj = rest >> 3;
  const ushort* A = ((pj & 1) ? x2T : x1T) + (size_t)b * SQ;
  const ushort* B = wbf + (size_t)pj * (C_DIM * C_DIM);
  const float* bias = pj == 0 ? b_q : pj == 1 ? b_k : pj == 2 ? b_v1 : b_v2;
  if (pj < 2) {
    ushort* oN = (pj == 0 ? q : kb) + (size_t)b * SQ;
    gemm_core128<false, false>(A, B, bias, oN, nullptr, C_DIM, C_DIM, C_DIM,
                               C_DIM, 0, x * 128, y * 128, 1.0f, 0, 0, nullptr);
  } else {
    ushort* oT = (pj == 2 ? v1T : v2T) + (size_t)b * SQ;
    gemm_core128<false, false>(A, B, bias, nullptr, oT, C_DIM, C_DIM, C_DIM,
                               0, L_DIM, x * 128, y * 128, 1.0f, 1, 0, nullptr);
  }
}

// P_unnorm = exp(q.k^T * scale) -> attn, attnT, partial sums.
// lid = x(16) | y(16) | b(8)
__global__ __launch_bounds__(256, 4) void gemm_qkt(
    const ushort* __restrict__ qb, const ushort* __restrict__ kb,
    ushort* __restrict__ attn, ushort* __restrict__ attnT, const float scale)
{
  const int lid = xcd_swz(blockIdx.x, 2048);
  const int x = lid & 15, y = (lid >> 4) & 15, b = lid >> 8;
  gemm_core128<true, false>(qb + (size_t)b * SQ, kb + (size_t)b * SQ, nullptr,
               attn + (size_t)b * SAT, attnT + (size_t)b * SAT,
               C_DIM, C_DIM, C_DIM, L_DIM, L_DIM,
               x * 128, y * 128, scale, 2, b, nullptr);
}

// both PVs (sm_combine fused in prologue): lid = x(16) | y(4) | which(2) | b(8)
__global__ __launch_bounds__(256, 4) void gemm_pv(
    const ushort* __restrict__ attn, const ushort* __restrict__ attnT,
    const ushort* __restrict__ v1T, const ushort* __restrict__ v2T,
    ushort* __restrict__ vk, ushort* __restrict__ vq)
{
  const int lid = xcd_swz(blockIdx.x, 1024);
  const int x = lid & 15, y = (lid >> 4) & 3, rest = lid >> 6;
  const int which = rest & 1, b = rest >> 1;
  const ushort* A = (which ? attnT : attn) + (size_t)b * SAT;
  const ushort* B = (which ? v1T : v2T) + (size_t)b * SQ;
  ushort* o = (which ? vq : vk) + (size_t)b * SQ;
  const int m0 = x * 128;
  const float* ps = (which ? &g_psc[0][0] : &g_psr[0][0]) + b * L_DIM + m0;
  gemm_core128<false, true>(A, B, nullptr, o, nullptr,
               L_DIM, L_DIM, L_DIM, C_DIM, 0,
               m0, y * 128, 1.0f, 0, b, ps);
}

// ---------------------------------------------------------------------------
// x [B][C][L] fp32 -> xT [B][L][C] bf16, both inputs in one dispatch.
// ---------------------------------------------------------------------------
__global__ __launch_bounds__(256) void xpose(const float* __restrict__ x1,
                                             const float* __restrict__ x2,
                                             ushort* __restrict__ xT)
{
  __shared__ float s[64][65];
  const int z = blockIdx.z, l0 = blockIdx.x * 64, c0 = blockIdx.y * 64;
  const int t = threadIdx.x;
  const float* xb = (z < 8 ? x1 : x2) + ((size_t)(z & 7) * C_DIM + c0) * L_DIM + l0;
  #pragma unroll
  for (int p = 0; p < 16; ++p) {
    const int c = p * 4 + (t >> 6);
    s[c][t & 63] = xb[(size_t)c * L_DIM + (t & 63)];
  }
  __syncthreads();
  ushort* ob = xT + (size_t)z * SQ + (size_t)l0 * C_DIM + c0;
  #pragma unroll
  for (int p = 0; p < 16; ++p) {
    const int l = p * 4 + (t >> 6);
    ob[(size_t)l * C_DIM + (t & 63)] = f2bf(s[t & 63][l]);
  }
}

// all 4 weights fp32 -> bf16 in one dispatch
__global__ __launch_bounds__(256) void cvtw4(const float* __restrict__ a,
    const float* __restrict__ b, const float* __restrict__ c,
    const float* __restrict__ d, ushort* __restrict__ o)
{
  const int i = blockIdx.x * 256 + threadIdx.x;
  const int sel = i >> 18;
  const float* w = sel == 0 ? a : sel == 1 ? b : sel == 2 ? c : d;
  o[i] = f2bf(w[i & 262143]);
}

// ---------------------------------------------------------------------------
// LayerNorm over C + cross skip + transpose back to (B, C, L).
// v2: 32 l-rows per block, bf16 LDS tile (33 KB) -> 128 B out-write segments.
// ---------------------------------------------------------------------------
__global__ __launch_bounds__(256) void ln_out(const ushort* __restrict__ vk,
    const ushort* __restrict__ vq, const float* __restrict__ x1,
    const float* __restrict__ x2, const float* __restrict__ gamma,
    const float* __restrict__ beta, float* __restrict__ out)
{
  __shared__ __align__(16) ushort s[32][520];   // bf16 (v + x), padded pitch
  __shared__ float mu[32], rsd[32];
  __shared__ float gb[512], bb[512];
  const int t = threadIdx.x;
  const int b = blockIdx.y, l0 = blockIdx.x * 32, which = blockIdx.z;
  const ushort* vx = which ? vq : vk;
  const float* xo = which ? x2 : x1;
  float* obase = out + (size_t)which * MC;
  #pragma unroll
  for (int r = 0; r < 2; ++r) { gb[r * 256 + t] = gamma[r * 256 + t]; bb[r * 256 + t] = beta[r * 256 + t]; }
  // 1) load v tile (bf16 passthrough, coalesced in c)
  const ushort* vb = vx + ((size_t)b * L_DIM + l0) * C_DIM;
  #pragma unroll
  for (int p = 0; p < 8; ++p) {
    const int id = p * 256 + t;             // 2048 chunks of 8 bf16
    const int l = id >> 6, cb = (id & 63) * 8;
    *(bf16x8*)&s[l][cb] = *(const bf16x8*)&vb[(size_t)l * C_DIM + cb];
  }
  __syncthreads();
  // 2) add skip (x read coalesced in l: 128 B segments)
  const float* xb = xo + (size_t)b * C_DIM * L_DIM + l0;
  for (int it = 0; it < 64; ++it) {
    const int idx = it * 256 + t, c = idx >> 5, l = idx & 31;
    s[l][c] = f2bf(bf2f(s[l][c]) + xb[(size_t)c * L_DIM + l]);
  }
  __syncthreads();
  // 3) stats: wave w handles rows w*8 .. w*8+7; lane covers 8 c's
  const int w = t >> 6, lane = t & 63;
  #pragma unroll
  for (int rr = 0; rr < 8; ++rr) {
    const int l = w * 8 + rr;
    const bf16x8 v8 = *(const bf16x8*)&s[l][lane * 8];
    float sum = 0.f, sq = 0.f;
    #pragma unroll
    for (int j = 0; j < 8; ++j) {
      const float v = bf2f((ushort)v8[j]);
      sum += v; sq = fmaf(v, v, sq);
    }
    sum = wave_red_sum(sum); sq = wave_red_sum(sq);
    if (lane == 0) {
      const float m = sum * (1.f / 512.f);
      const float var = sq * (1.f / 512.f) - m * m;
      mu[l] = m; rsd[l] = rsqrtf(var + 1e-5f);
    }
  }
  __syncthreads();
  // 4) normalize + write (coalesced in l: 128 B segments)
  float* ob = obase + (size_t)b * C_DIM * L_DIM + l0;
  for (int it = 0; it < 64; ++it) {
    const int idx = it * 256 + t, c = idx >> 5, l = idx & 31;
    const float v = (bf2f(s[l][c]) - mu[l]) * rsd[l] * gb[c] + bb[c];
    ob[(size_t)c * L_DIM + l] = v;
  }
}

// ---------------------------------------------------------------------------
extern "C" void kernel_launch(void* const* d_in, const int* in_sizes, int n_in,
                              void* d_out, int out_size, void* d_ws, size_t ws_size,
                              hipStream_t stream) {
  const float* x1   = (const float*)d_in[0];
  const float* x2   = (const float*)d_in[1];
  const float* w_q  = (const float*)d_in[2];
  const float* b_q  = (const float*)d_in[3];
  const float* w_k  = (const float*)d_in[4];
  const float* b_k  = (const float*)d_in[5];
  const float* w_v1 = (const float*)d_in[6];
  const float* b_v1 = (const float*)d_in[7];
  const float* w_v2 = (const float*)d_in[8];
  const float* b_v2 = (const float*)d_in[9];
  const float* gamma= (const float*)d_in[10];
  const float* beta = (const float*)d_in[11];
  float* out = (float*)d_out;

  // ---- ws: exactly 128 MiB bf16 ----
  ushort* q    = (ushort*)d_ws;        // 16 MiB
  ushort* kbuf = q + MC;               // 16 MiB
  ushort* v1T  = kbuf + MC;            // 16 MiB  [C][L] per batch
  ushort* v2T  = v1T + MC;             // 16 MiB
  ushort* attn = v2T + MC;             // 64 MiB  [q][k] per batch (P_unnorm)
  // overlays in the not-yet-written attn region (dead before QK^T):
  ushort* x1T = attn;                  // 16 MiB  [B][L][C]  (x2T = x1T + MC)
  ushort* wbf = attn + 2 * MC;         // 4 x 256K = 2 MiB (q|k|v1|v2)
  // PV outputs in regions dead after QK^T:
  ushort* vkbuf = kbuf;
  ushort* vqbuf = q;
  // attnT [k][q] bf16 fills d_out (64 MiB), dead before ln writes:
  ushort* attnT = (ushort*)d_out;

  const float iscale = 0.044194173824159216f;  // 1/sqrt(512)
  const dim3 blk256(256);

  // 1) weights fp32 -> bf16
  cvtw4<<<4096, blk256, 0, stream>>>(w_q, w_k, w_v1, w_v2, wbf);
  // 2) x1,x2 -> xT bf16
  xpose<<<dim3(32, 8, 16), blk256, 0, stream>>>(x1, x2, x1T);
  // 3) all 4 projections
  gemm_proj<<<2048, blk256, 0, stream>>>(x1T, x1T + MC, wbf,
      b_q, b_k, b_v1, b_v2, q, kbuf, v1T, v2T);
  // 4) P_unnorm = exp(q.k^T * iscale) -> attn, attnT + partial sums
  gemm_qkt<<<2048, blk256, 0, stream>>>(q, kbuf, attn, attnT, iscale);
  // 5) both PVs (sm_combine fused into pv prologue)
  gemm_pv<<<1024, blk256, 0, stream>>>(attn, attnT, v1T, v2T, vkbuf, vqbuf);
  // 6) LN + skip + transpose back (clobbers attnT -- now dead)
  ln_out<<<dim3(L_DIM / 32, B_DIM, 2), blk256, 0, stream>>>(
      vkbuf, vqbuf, x1, x2, gamma, beta, out);
}

// Round 16
// 236.810 us; speedup vs baseline: 1.1416x; 1.0119x over previous
//
#include <hip/hip_runtime.h>

#define L_DIM 2048
#define C_DIM 512
#define B_DIM 8

typedef __attribute__((ext_vector_type(8))) short bf16x8;   // 8 bf16 = 4 VGPR
typedef __attribute__((ext_vector_type(4))) float f32x4;    // MFMA acc

constexpr size_t SQ  = (size_t)L_DIM * C_DIM;   // per-batch q/k/v stride
constexpr size_t SAT = (size_t)L_DIM * L_DIM;   // per-batch attn stride
constexpr size_t MC  = (size_t)B_DIM * L_DIM * C_DIM;
constexpr int BL = B_DIM * L_DIM;               // 16384

// softmax scratch (device globals -- no ws footprint, rewritten every launch)
__device__ float g_psr[16][BL];   // row partial expsum [ktile][b*L+row]
__device__ float g_psc[16][BL];   // col partial expsum [qtile][b*L+col]

__device__ __forceinline__ float bf2f(ushort u) {
  union { float f; unsigned int i; } c; c.i = ((unsigned int)u) << 16; return c.f;
}
__device__ __forceinline__ ushort f2bf(float f) {
  union { float f; unsigned int i; } c; c.f = f;
  unsigned int lsb = (c.i >> 16) & 1u;
  return (ushort)((c.i + 0x7FFFu + lsb) >> 16);
}

__device__ __forceinline__ float wave_red_sum(float v) {
  #pragma unroll
  for (int o = 1; o < 64; o <<= 1) v += __shfl_xor(v, o, 64);
  return v;
}

// async global->LDS, 16B per lane (dest = wave-uniform base + lane*16)
__device__ __forceinline__ void glds16(const ushort* g, ushort* l) {
  __builtin_amdgcn_global_load_lds(
      (const __attribute__((address_space(1))) void*)g,
      (__attribute__((address_space(3))) void*)l, 16, 0, 0);
}

// LDS slot functions: row-group rotation spreads 16 consecutive rows over all
// 8 bank-quads (2-way aliasing = free). Bijective in c for fixed r.
__device__ __forceinline__ int slotAB(int r, int c) {          // c = 16B chunk 0..7
  return (((c ^ (r & 7)) + (r >> 3)) & 7);
}
__device__ __forceinline__ int chAB(int r, int sl) {           // inverse
  return ((sl - (r >> 3)) & 7) ^ (r & 7);
}
__device__ __forceinline__ int slotC(int r, int q4) {          // q4 = c>>3, 0..15
  return ((q4 ^ (r & 15)) + (r >> 4)) & 15;
}

// XCD-chunked swizzle (T1). nwg % 8 == 0.
__device__ __forceinline__ int xcd_swz(int bid, int nwg) {
  return (bid & 7) * (nwg >> 3) + (bid >> 3);
}

// ---------------------------------------------------------------------------
// 128x128 bf16 MFMA GEMM core, D = A.B^T. BK=64, 256 thr = 4 waves (2x2),
// single-buffered 32 KiB LDS (m97 structure), glds staging both operands.
// STATS (qkt): epilogue stores exp(val); ROW partials via vectorized Cs scan;
//              COL partials in-register during the bounce (each acc frag holds
//              4 rows of ONE column) -> shuffle over lhi + 2-wave LDS add.
// SCALE (pv):  prologue folds sm_combine (sum 16 partials -> 1/s into LDS);
//              epilogue multiplies by sinv[row].
// EPI: 0 row-major store (obN,ldo), 1 transposed (obT,ldoT), 2 both.
// ---------------------------------------------------------------------------
template <bool STATS, bool SCALE>
__device__ __forceinline__ void gemm_core128(
    const ushort* __restrict__ Ab, const ushort* __restrict__ Bb,
    const float* __restrict__ bias,
    ushort* __restrict__ obN, ushort* __restrict__ obT,
    const int K, const int lda, const int ldb, const int ldo, const int ldoT,
    const int m0, const int n0, const float scale, const int EPI,
    const int sb, const float* __restrict__ ps)   // ps: pre-offset partials (16 x BL)
{
  __shared__ __align__(16) ushort lds[16384];   // 32 KiB: A 8K | B 8K ushorts
  __shared__ float sinv[128];
  __shared__ float colp[2][128];                // col partials per wave-row half

  const int t = threadIdx.x;
  const int lane = t & 63, w = t >> 6;
  const int wr = w >> 1, wc = w & 1;
  const int l16 = lane & 15, lhi = lane >> 4;
  const int lrow = lane >> 3, lsl = lane & 7;

  ushort* As = lds;
  ushort* Bs = lds + 8192;

  // fused sm_combine: 1/sum for this block's 128 rows (sinv read only in the
  // epilogue, after multiple barriers -> ordering safe).
  if (SCALE) {
    if (t < 128) {
      float s = 0.f;
      #pragma unroll
      for (int p = 0; p < 16; ++p) s += ps[(size_t)p * BL + t];
      sinv[t] = 1.0f / s;
    }
  }

  f32x4 acc[4][4];
  #pragma unroll
  for (int i = 0; i < 4; ++i)
    #pragma unroll
    for (int j = 0; j < 4; ++j) { f32x4 zv = {0.f, 0.f, 0.f, 0.f}; acc[i][j] = zv; }

  const int KT = K >> 6;
  for (int kt = 0; kt < KT; ++kt) {
    const int k0 = kt << 6;
    __syncthreads();                       // prev compute done with LDS
    #pragma unroll
    for (int p = 0; p < 4; ++p) {
      const int rbase = w * 32 + p * 8;
      const int rr = rbase + lrow;
      const int ch = chAB(rr, lsl);        // inverse-swizzled global source
      glds16(Ab + (size_t)(m0 + rr) * lda + k0 + ch * 8, As + rbase * 64);
      glds16(Bb + (size_t)(n0 + rr) * ldb + k0 + ch * 8, Bs + rbase * 64);
    }
    __syncthreads();                       // drains vmcnt -> LDS ready
    #pragma unroll
    for (int ks = 0; ks < 2; ++ks) {
      bf16x8 af[4], bg[4];
      #pragma unroll
      for (int i = 0; i < 4; ++i) {
        const int ra = wr * 64 + i * 16 + l16;
        af[i] = *(const bf16x8*)&As[ra * 64 + 8 * slotAB(ra, ks * 4 + lhi)];
        const int rb = wc * 64 + i * 16 + l16;
        bg[i] = *(const bf16x8*)&Bs[rb * 64 + 8 * slotAB(rb, ks * 4 + lhi)];
      }
      #pragma unroll
      for (int i = 0; i < 4; ++i)
        #pragma unroll
        for (int j = 0; j < 4; ++j)
          acc[i][j] = __builtin_amdgcn_mfma_f32_16x16x32_bf16(af[i], bg[j], acc[i][j], 0, 0, 0);
    }
  }

  // ---- epilogue: bounce C tile (128x128 bf16) through swizzled LDS ----
  __syncthreads();
  ushort* Cs = lds;                        // 32 KiB
  float csum[4] = {0.f, 0.f, 0.f, 0.f};    // per-thread col partials (STATS)
  #pragma unroll
  for (int i = 0; i < 4; ++i) {
    #pragma unroll
    for (int j = 0; j < 4; ++j) {
      const int er = wr * 64 + i * 16 + lhi * 4;       // C/D: row=(lane>>4)*4+reg
      const int ec = wc * 64 + j * 16 + l16;           //      col=lane&15
      const float bv = bias ? bias[n0 + ec] : 0.f;
      #pragma unroll
      for (int r = 0; r < 4; ++r) {
        const int rr = er + r;
        float val = acc[i][j][r] * scale + bv;
        if (STATS) { val = __expf(val); csum[j] += val; }  // P_unnorm = exp(score)
        if (SCALE) val *= sinv[rr];
        Cs[rr * 128 + 8 * slotC(rr, ec >> 3) + (ec & 7)] = f2bf(val);
      }
    }
  }
  if (STATS) {
    // reduce csum over the 4 lhi lanes sharing each column (same wc,j,l16),
    // then publish per-wave-row-half sums to colp for the cross-wr add.
    #pragma unroll
    for (int j = 0; j < 4; ++j) {
      float v = csum[j];
      v += __shfl_xor(v, 16, 64);
      v += __shfl_xor(v, 32, 64);
      if (lhi == 0) colp[wr][wc * 64 + j * 16 + l16] = v;
    }
  }
  __syncthreads();
  if (EPI == 0 || EPI == 2) {
    #pragma unroll
    for (int p = 0; p < 8; ++p) {
      const int id = p * 256 + t, r = id >> 4, cc = id & 15;
      const bf16x8 v = *(const bf16x8*)&Cs[r * 128 + 8 * slotC(r, cc)];
      *(bf16x8*)(obN + (size_t)(m0 + r) * ldo + n0 + cc * 8) = v;
    }
  }
  if (EPI >= 1) {
    #pragma unroll
    for (int p = 0; p < 8; ++p) {
      const int id = p * 256 + t, c = id >> 4, rs = id & 15;
      bf16x8 tv;
      #pragma unroll
      for (int jj = 0; jj < 8; ++jj) {
        const int r2 = rs * 8 + jj;
        tv[jj] = (short)Cs[r2 * 128 + 8 * slotC(r2, c >> 3) + (c & 7)];
      }
      *(bf16x8*)(obT + (size_t)(n0 + c) * ldoT + m0 + rs * 8) = tv;
    }
  }

  if (STATS) {
    if (t < 128) {                          // row partials: vectorized Cs scan
      const int r = t;
      float s = 0.f;
      #pragma unroll
      for (int cc = 0; cc < 16; ++cc) {
        const bf16x8 v8 = *(const bf16x8*)&Cs[r * 128 + 8 * slotC(r, cc)];
        #pragma unroll
        for (int j = 0; j < 8; ++j) s += bf2f((ushort)v8[j]);
      }
      g_psr[n0 >> 7][sb * L_DIM + m0 + r] = s;
    } else {                                // col partials: colp finalize
      const int c = t - 128;
      g_psc[m0 >> 7][sb * L_DIM + n0 + c] = colp[0][c] + colp[1][c];
    }
  }
}

// ---- wrappers (1D grids + XCD swizzle) -------------------------------------
// all 4 projections: lid = x(16) | y(4) | b(8) | pj(4)
__global__ __launch_bounds__(256, 4) void gemm_proj(
    const ushort* __restrict__ x1T, const ushort* __restrict__ x2T,
    const ushort* __restrict__ wbf,
    const float* __restrict__ b_q, const float* __restrict__ b_k,
    const float* __restrict__ b_v1, const float* __restrict__ b_v2,
    ushort* __restrict__ q, ushort* __restrict__ kb,
    ushort* __restrict__ v1T, ushort* __restrict__ v2T)
{
  const int lid = xcd_swz(blockIdx.x, 2048);
  const int x = lid & 15, y = (lid >> 4) & 3, rest = lid >> 6;
  const int b = rest & 7, pj = rest >> 3;
  const ushort* A = ((pj & 1) ? x2T : x1T) + (size_t)b * SQ;
  const ushort* B = wbf + (size_t)pj * (C_DIM * C_DIM);
  const float* bias = pj == 0 ? b_q : pj == 1 ? b_k : pj == 2 ? b_v1 : b_v2;
  if (pj < 2) {
    ushort* oN = (pj == 0 ? q : kb) + (size_t)b * SQ;
    gemm_core128<false, false>(A, B, bias, oN, nullptr, C_DIM, C_DIM, C_DIM,
                               C_DIM, 0, x * 128, y * 128, 1.0f, 0, 0, nullptr);
  } else {
    ushort* oT = (pj == 2 ? v1T : v2T) + (size_t)b * SQ;
    gemm_core128<false, false>(A, B, bias, nullptr, oT, C_DIM, C_DIM, C_DIM,
                               0, L_DIM, x * 128, y * 128, 1.0f, 1, 0, nullptr);
  }
}

// P_unnorm = exp(q.k^T * scale) -> attn, attnT, partial sums.
// lid = x(16) | y(16) | b(8)
__global__ __launch_bounds__(256, 4) void gemm_qkt(
    const ushort* __restrict__ qb, const ushort* __restrict__ kb,
    ushort* __restrict__ attn, ushort* __restrict__ attnT, const float scale)
{
  const int lid = xcd_swz(blockIdx.x, 2048);
  const int x = lid & 15, y = (lid >> 4) & 15, b = lid >> 8;
  gemm_core128<true, false>(qb + (size_t)b * SQ, kb + (size_t)b * SQ, nullptr,
               attn + (size_t)b * SAT, attnT + (size_t)b * SAT,
               C_DIM, C_DIM, C_DIM, L_DIM, L_DIM,
               x * 128, y * 128, scale, 2, b, nullptr);
}

// both PVs (sm_combine fused in prologue): lid = x(16) | y(4) | which(2) | b(8)
__global__ __launch_bounds__(256, 4) void gemm_pv(
    const ushort* __restrict__ attn, const ushort* __restrict__ attnT,
    const ushort* __restrict__ v1T, const ushort* __restrict__ v2T,
    ushort* __restrict__ vk, ushort* __restrict__ vq)
{
  const int lid = xcd_swz(blockIdx.x, 1024);
  const int x = lid & 15, y = (lid >> 4) & 3, rest = lid >> 6;
  const int which = rest & 1, b = rest >> 1;
  const ushort* A = (which ? attnT : attn) + (size_t)b * SAT;
  const ushort* B = (which ? v1T : v2T) + (size_t)b * SQ;
  ushort* o = (which ? vq : vk) + (size_t)b * SQ;
  const int m0 = x * 128;
  const float* ps = (which ? &g_psc[0][0] : &g_psr[0][0]) + b * L_DIM + m0;
  gemm_core128<false, true>(A, B, nullptr, o, nullptr,
               L_DIM, L_DIM, L_DIM, C_DIM, 0,
               m0, y * 128, 1.0f, 0, b, ps);
}

// ---------------------------------------------------------------------------
// x [B][C][L] fp32 -> xT [B][L][C] bf16, both inputs in one dispatch.
// ---------------------------------------------------------------------------
__global__ __launch_bounds__(256) void xpose(const float* __restrict__ x1,
                                             const float* __restrict__ x2,
                                             ushort* __restrict__ xT)
{
  __shared__ float s[64][65];
  const int z = blockIdx.z, l0 = blockIdx.x * 64, c0 = blockIdx.y * 64;
  const int t = threadIdx.x;
  const float* xb = (z < 8 ? x1 : x2) + ((size_t)(z & 7) * C_DIM + c0) * L_DIM + l0;
  #pragma unroll
  for (int p = 0; p < 16; ++p) {
    const int c = p * 4 + (t >> 6);
    s[c][t & 63] = xb[(size_t)c * L_DIM + (t & 63)];
  }
  __syncthreads();
  ushort* ob = xT + (size_t)z * SQ + (size_t)l0 * C_DIM + c0;
  #pragma unroll
  for (int p = 0; p < 16; ++p) {
    const int l = p * 4 + (t >> 6);
    ob[(size_t)l * C_DIM + (t & 63)] = f2bf(s[t & 63][l]);
  }
}

// all 4 weights fp32 -> bf16 in one dispatch
__global__ __launch_bounds__(256) void cvtw4(const float* __restrict__ a,
    const float* __restrict__ b, const float* __restrict__ c,
    const float* __restrict__ d, ushort* __restrict__ o)
{
  const int i = blockIdx.x * 256 + threadIdx.x;
  const int sel = i >> 18;
  const float* w = sel == 0 ? a : sel == 1 ? b : sel == 2 ? c : d;
  o[i] = f2bf(w[i & 262143]);
}

// ---------------------------------------------------------------------------
// LayerNorm over C + cross skip + transpose back to (B, C, L).
// v2: 32 l-rows per block, bf16 LDS tile (33 KB) -> 128 B out-write segments.
// ---------------------------------------------------------------------------
__global__ __launch_bounds__(256) void ln_out(const ushort* __restrict__ vk,
    const ushort* __restrict__ vq, const float* __restrict__ x1,
    const float* __restrict__ x2, const float* __restrict__ gamma,
    const float* __restrict__ beta, float* __restrict__ out)
{
  __shared__ __align__(16) ushort s[32][520];   // bf16 (v + x), padded pitch
  __shared__ float mu[32], rsd[32];
  __shared__ float gb[512], bb[512];
  const int t = threadIdx.x;
  const int b = blockIdx.y, l0 = blockIdx.x * 32, which = blockIdx.z;
  const ushort* vx = which ? vq : vk;
  const float* xo = which ? x2 : x1;
  float* obase = out + (size_t)which * MC;
  #pragma unroll
  for (int r = 0; r < 2; ++r) { gb[r * 256 + t] = gamma[r * 256 + t]; bb[r * 256 + t] = beta[r * 256 + t]; }
  // 1) load v tile (bf16 passthrough, coalesced in c)
  const ushort* vb = vx + ((size_t)b * L_DIM + l0) * C_DIM;
  #pragma unroll
  for (int p = 0; p < 8; ++p) {
    const int id = p * 256 + t;             // 2048 chunks of 8 bf16
    const int l = id >> 6, cb = (id & 63) * 8;
    *(bf16x8*)&s[l][cb] = *(const bf16x8*)&vb[(size_t)l * C_DIM + cb];
  }
  __syncthreads();
  // 2) add skip (x read coalesced in l: 128 B segments)
  const float* xb = xo + (size_t)b * C_DIM * L_DIM + l0;
  for (int it = 0; it < 64; ++it) {
    const int idx = it * 256 + t, c = idx >> 5, l = idx & 31;
    s[l][c] = f2bf(bf2f(s[l][c]) + xb[(size_t)c * L_DIM + l]);
  }
  __syncthreads();
  // 3) stats: wave w handles rows w*8 .. w*8+7; lane covers 8 c's
  const int w = t >> 6, lane = t & 63;
  #pragma unroll
  for (int rr = 0; rr < 8; ++rr) {
    const int l = w * 8 + rr;
    const bf16x8 v8 = *(const bf16x8*)&s[l][lane * 8];
    float sum = 0.f, sq = 0.f;
    #pragma unroll
    for (int j = 0; j < 8; ++j) {
      const float v = bf2f((ushort)v8[j]);
      sum += v; sq = fmaf(v, v, sq);
    }
    sum = wave_red_sum(sum); sq = wave_red_sum(sq);
    if (lane == 0) {
      const float m = sum * (1.f / 512.f);
      const float var = sq * (1.f / 512.f) - m * m;
      mu[l] = m; rsd[l] = rsqrtf(var + 1e-5f);
    }
  }
  __syncthreads();
  // 4) normalize + write (coalesced in l: 128 B segments)
  float* ob = obase + (size_t)b * C_DIM * L_DIM + l0;
  for (int it = 0; it < 64; ++it) {
    const int idx = it * 256 + t, c = idx >> 5, l = idx & 31;
    const float v = (bf2f(s[l][c]) - mu[l]) * rsd[l] * gb[c] + bb[c];
    ob[(size_t)c * L_DIM + l] = v;
  }
}

// ---------------------------------------------------------------------------
extern "C" void kernel_launch(void* const* d_in, const int* in_sizes, int n_in,
                              void* d_out, int out_size, void* d_ws, size_t ws_size,
                              hipStream_t stream) {
  const float* x1   = (const float*)d_in[0];
  const float* x2   = (const float*)d_in[1];
  const float* w_q  = (const float*)d_in[2];
  const float* b_q  = (const float*)d_in[3];
  const float* w_k  = (const float*)d_in[4];
  const float* b_k  = (const float*)d_in[5];
  const float* w_v1 = (const float*)d_in[6];
  const float* b_v1 = (const float*)d_in[7];
  const float* w_v2 = (const float*)d_in[8];
  const float* b_v2 = (const float*)d_in[9];
  const float* gamma= (const float*)d_in[10];
  const float* beta = (const float*)d_in[11];
  float* out = (float*)d_out;

  // ---- ws: exactly 128 MiB bf16 ----
  ushort* q    = (ushort*)d_ws;        // 16 MiB
  ushort* kbuf = q + MC;               // 16 MiB
  ushort* v1T  = kbuf + MC;            // 16 MiB  [C][L] per batch
  ushort* v2T  = v1T + MC;             // 16 MiB
  ushort* attn = v2T + MC;             // 64 MiB  [q][k] per batch (P_unnorm)
  // overlays in the not-yet-written attn region (dead before QK^T):
  ushort* x1T = attn;                  // 16 MiB  [B][L][C]  (x2T = x1T + MC)
  ushort* wbf = attn + 2 * MC;         // 4 x 256K = 2 MiB (q|k|v1|v2)
  // PV outputs in regions dead after QK^T:
  ushort* vkbuf = kbuf;
  ushort* vqbuf = q;
  // attnT [k][q] bf16 fills d_out (64 MiB), dead before ln writes:
  ushort* attnT = (ushort*)d_out;

  const float iscale = 0.044194173824159216f;  // 1/sqrt(512)
  const dim3 blk256(256);

  // 1) weights fp32 -> bf16
  cvtw4<<<4096, blk256, 0, stream>>>(w_q, w_k, w_v1, w_v2, wbf);
  // 2) x1,x2 -> xT bf16
  xpose<<<dim3(32, 8, 16), blk256, 0, stream>>>(x1, x2, x1T);
  // 3) all 4 projections
  gemm_proj<<<2048, blk256, 0, stream>>>(x1T, x1T + MC, wbf,
      b_q, b_k, b_v1, b_v2, q, kbuf, v1T, v2T);
  // 4) P_unnorm = exp(q.k^T * iscale) -> attn, attnT + partial sums
  gemm_qkt<<<2048, blk256, 0, stream>>>(q, kbuf, attn, attnT, iscale);
  // 5) both PVs (sm_combine fused into pv prologue)
  gemm_pv<<<1024, blk256, 0, stream>>>(attn, attnT, v1T, v2T, vkbuf, vqbuf);
  // 6) LN + skip + transpose back (clobbers attnT -- now dead)
  ln_out<<<dim3(L_DIM / 32, B_DIM, 2), blk256, 0, stream>>>(
      vkbuf, vqbuf, x1, x2, gamma, beta, out);
}